// Round 3
// baseline (359.514 us; speedup 1.0000x reference)
//
#include <hip/hip_runtime.h>
#include <math.h>

// QuantumIntegrator: r_embed [B=4, S=4096, 2] float32, dt [4] float32.
// Outputs (flat FLOAT32): r_final [4,4096,2] then score [4,4096,4096].
//   (R2 post-mortem: harness reads d_out as float32 — reference output dtype.
//    Error 4.0078 = 2.0 + 2.0078 was packed-bf16 reinterpreted as f32.)
//
// Per row s (per batch): denom = sum_{t<=s} relu(r_s.r_t),
// numer = sum_{t<=s} relu(r_s.r_t) r_t. score row = relu(r_s.r_t)/max(denom,eps).
// k1 = dt*numer/max(denom,eps); r_mid = r + k1; same reduction on r_mid -> k2;
// r_new = r + 0.5(k1+k2); radius clamp -> r_final.
//
// The 268 MB fp32 score write dominates; floor ~43 us at 6.3 TB/s.

#define S_LEN 4096
#define ROWS  16384   // B*S with B=4 (fixed by setup_inputs)
#define BLK   256
#define EPSF  1e-6f
#define RATE  0.01f
#define MINR  0.1f
#define MAXR  2.0f

// Reduce 3 floats across the 256-thread block. Result valid in thread 0 only.
__device__ __forceinline__ void reduce3(float &a, float &b, float &c, float* red) {
    #pragma unroll
    for (int off = 32; off > 0; off >>= 1) {
        a += __shfl_down(a, off);
        b += __shfl_down(b, off);
        c += __shfl_down(c, off);
    }
    const int wave = threadIdx.x >> 6;
    if ((threadIdx.x & 63) == 0) { red[wave*3] = a; red[wave*3+1] = b; red[wave*3+2] = c; }
    __syncthreads();
    if (threadIdx.x == 0) {
        a = red[0] + red[3] + red[6] + red[9];
        b = red[1] + red[4] + red[7] + red[10];
        c = red[2] + red[5] + red[8] + red[11];
    }
}

// ws layout (floats): [0, 2*ROWS) r_mid; [2*ROWS, 4*ROWS) k1; [4*ROWS, 5*ROWS) sum_score.

__global__ __launch_bounds__(BLK) void k_pass1(
    const float2* __restrict__ r_in,              // fp32 (x,y) per (b,s)
    const float* __restrict__ dt_in,              // fp32 per batch
    float* __restrict__ ws,
    float* __restrict__ score_out)                // fp32, [ROWS, S_LEN]
{
    __shared__ float2 sh[S_LEN];
    __shared__ float red[12];
    __shared__ float bc[1];

    const int row = blockIdx.x;
    const int b = row >> 12;
    const int s = row & (S_LEN - 1);
    const float2* rb = r_in + ((size_t)b << 12);

    // Stage r[b][0..s] into LDS (t>s never read).
    for (int t = threadIdx.x; t <= s; t += BLK) sh[t] = rb[t];
    __syncthreads();

    const float2 rs = sh[s];
    float dsum = 0.f, nx = 0.f, ny = 0.f;
    for (int t = threadIdx.x; t <= s; t += BLK) {
        float2 rt = sh[t];
        float d = fmaxf(rs.x * rt.x + rs.y * rt.y, 0.f);
        dsum += d;
        nx = fmaf(d, rt.x, nx);
        ny = fmaf(d, rt.y, ny);
    }
    reduce3(dsum, nx, ny, red);
    if (threadIdx.x == 0) {
        const float D  = dsum;
        const float dc = fmaxf(D, EPSF);
        const float dtb = dt_in[b];
        float k1x = dtb * nx / dc;
        float k1y = dtb * ny / dc;
        if (!isfinite(k1x)) k1x = 0.f;
        if (!isfinite(k1y)) k1y = 0.f;
        float rmx = rs.x + k1x, rmy = rs.y + k1y;
        if (!isfinite(rmx)) rmx = rs.x;
        if (!isfinite(rmy)) rmy = rs.y;
        float* rmid = ws;
        float* k1w  = ws + 2 * ROWS;
        float* s1w  = ws + 4 * ROWS;
        rmid[2*row]   = rmx; rmid[2*row+1] = rmy;
        k1w[2*row]    = k1x; k1w[2*row+1]  = k1y;
        s1w[row]      = D / dc;      // == sum of normalized score row
        bc[0]         = 1.f / dc;
    }
    __syncthreads();
    const float inv = bc[0];

    // Write the 4096-wide fp32 score row: 16 floats per thread, 4 dwordx4 stores.
    const int t0 = threadIdx.x * 16;
    float4* op = (float4*)(score_out + (size_t)row * S_LEN + t0);
    #pragma unroll
    for (int q = 0; q < 4; q++) {
        float v[4];
        #pragma unroll
        for (int j = 0; j < 4; j++) {
            const int t = t0 + 4*q + j;
            float x = 0.f;
            if (t <= s) { float2 rt = sh[t]; x = fmaxf(rs.x*rt.x + rs.y*rt.y, 0.f) * inv; }
            v[j] = x;
        }
        op[q] = make_float4(v[0], v[1], v[2], v[3]);
    }
}

__global__ __launch_bounds__(BLK) void k_pass2(
    const float2* __restrict__ r_in,
    const float* __restrict__ dt_in,
    const float* __restrict__ ws,
    float* __restrict__ rfinal_out)               // fp32, [ROWS, 2]
{
    __shared__ float2 sh[S_LEN];
    __shared__ float red[12];

    const int row = blockIdx.x;
    const int b = row >> 12;
    const int s = row & (S_LEN - 1);
    const float2* rmid_b = ((const float2*)ws) + ((size_t)b << 12);

    for (int t = threadIdx.x; t <= s; t += BLK) sh[t] = rmid_b[t];
    __syncthreads();

    const float2 rs = sh[s];
    float dsum = 0.f, nx = 0.f, ny = 0.f;
    for (int t = threadIdx.x; t <= s; t += BLK) {
        float2 rt = sh[t];
        float d = fmaxf(rs.x * rt.x + rs.y * rt.y, 0.f);
        dsum += d;
        nx = fmaf(d, rt.x, nx);
        ny = fmaf(d, rt.y, ny);
    }
    reduce3(dsum, nx, ny, red);
    if (threadIdx.x == 0) {
        const float* k1w = ws + 2 * ROWS;
        const float* s1w = ws + 4 * ROWS;
        const float dc = fmaxf(dsum, EPSF);
        const float dtb = dt_in[b];
        float k2x = dtb * nx / dc;
        float k2y = dtb * ny / dc;
        if (!isfinite(k2x)) k2x = 0.f;
        if (!isfinite(k2y)) k2y = 0.f;
        const float2 r0 = r_in[row];
        const float k1x = k1w[2*row], k1y = k1w[2*row+1];
        const float rnx = r0.x + 0.5f * (k1x + k2x);
        const float rny = r0.y + 0.5f * (k1y + k2y);
        const float nr = fmaxf(sqrtf(rnx*rnx + rny*rny), EPSF);
        const float ar = fminf(fmaxf(nr + s1w[row] * RATE, MINR), MAXR);
        const float sc = ar / nr;
        float fx = rnx * sc, fy = rny * sc;
        if (!isfinite(fx)) fx = r0.x;
        if (!isfinite(fy)) fy = r0.y;
        rfinal_out[2*row]   = fx;
        rfinal_out[2*row+1] = fy;
    }
}

extern "C" void kernel_launch(void* const* d_in, const int* in_sizes, int n_in,
                              void* d_out, int out_size, void* d_ws, size_t ws_size,
                              hipStream_t stream) {
    const float2* r_in  = (const float2*)d_in[0];   // fp32 [4,4096,2]
    const float*  dt_in = (const float*)d_in[1];    // fp32 [4]
    float* out = (float*)d_out;
    float* ws  = (float*)d_ws;

    // d_out: first ROWS*2 floats = r_final, then ROWS*S_LEN floats = score.
    float* rfinal_out = out;
    float* score_out  = out + (size_t)2 * ROWS;

    hipLaunchKernelGGL(k_pass1, dim3(ROWS), dim3(BLK), 0, stream,
                       r_in, dt_in, ws, score_out);
    hipLaunchKernelGGL(k_pass2, dim3(ROWS), dim3(BLK), 0, stream,
                       r_in, dt_in, ws, rfinal_out);
}

// Round 4
// 273.447 us; speedup vs baseline: 1.3148x; 1.3148x over previous
//
#include <hip/hip_runtime.h>
#include <math.h>

// QuantumIntegrator: r_embed [B=4, S=4096, 2] float32, dt [4] float32.
// Outputs (flat float32): r_final [4,4096,2] then score [4,4096,4096].
//
// R3 post-mortem: LDS write-phase reads were 64-way bank-conflicted
// (lane byte-stride 128 -> all lanes same bank). This version drops LDS
// entirely: per-batch r is 32 KB (one L1), all reads are coalesced global
// loads; score stores are column-interleaved so each wave store covers a
// contiguous 1 KB segment. 268 MB fp32 write floor ~41 us @ 6.6 TB/s.

#define S_LEN 4096
#define ROWS  16384   // B*S with B=4 (fixed by setup_inputs)
#define BLK   256
#define EPSF  1e-6f
#define RATE  0.01f
#define MINR  0.1f
#define MAXR  2.0f

// Reduce 3 floats across the 256-thread block. Result valid in thread 0 only.
__device__ __forceinline__ void reduce3(float &a, float &b, float &c, float* red) {
    #pragma unroll
    for (int off = 32; off > 0; off >>= 1) {
        a += __shfl_down(a, off);
        b += __shfl_down(b, off);
        c += __shfl_down(c, off);
    }
    const int wave = threadIdx.x >> 6;
    if ((threadIdx.x & 63) == 0) { red[wave*3] = a; red[wave*3+1] = b; red[wave*3+2] = c; }
    __syncthreads();
    if (threadIdx.x == 0) {
        a = red[0] + red[3] + red[6] + red[9];
        b = red[1] + red[4] + red[7] + red[10];
        c = red[2] + red[5] + red[8] + red[11];
    }
}

// ws layout (floats): [0, 2*ROWS) r_mid; [2*ROWS, 4*ROWS) k1; [4*ROWS, 5*ROWS) sum_score.

__global__ __launch_bounds__(BLK) void k_pass1(
    const float2* __restrict__ r_in,              // fp32 (x,y) per (b,s)
    const float* __restrict__ dt_in,              // fp32 per batch
    float* __restrict__ ws,
    float* __restrict__ score_out)                // fp32, [ROWS, S_LEN]
{
    __shared__ float red[12];
    __shared__ float bc[1];

    const int row = blockIdx.x;
    const int b = row >> 12;
    const int s = row & (S_LEN - 1);
    const float2* rb = r_in + ((size_t)b << 12);
    const float4* rb4 = (const float4*)rb;        // one float4 = points (2i, 2i+1)
    const float2 rs = rb[s];

    // Triangular reduction: denom, numer. Coalesced float4 loads (L1-hot).
    float dsum = 0.f, nx = 0.f, ny = 0.f;
    for (int i = threadIdx.x; 2*i <= s; i += BLK) {
        float4 p = rb4[i];
        float d0 = fmaxf(rs.x * p.x + rs.y * p.y, 0.f);   // t = 2i (always <= s here)
        dsum += d0; nx = fmaf(d0, p.x, nx); ny = fmaf(d0, p.y, ny);
        if (2*i + 1 <= s) {
            float d1 = fmaxf(rs.x * p.z + rs.y * p.w, 0.f);
            dsum += d1; nx = fmaf(d1, p.z, nx); ny = fmaf(d1, p.w, ny);
        }
    }
    reduce3(dsum, nx, ny, red);
    if (threadIdx.x == 0) {
        const float D  = dsum;
        const float dc = fmaxf(D, EPSF);
        const float dtb = dt_in[b];
        float k1x = dtb * nx / dc;
        float k1y = dtb * ny / dc;
        if (!isfinite(k1x)) k1x = 0.f;
        if (!isfinite(k1y)) k1y = 0.f;
        float rmx = rs.x + k1x, rmy = rs.y + k1y;
        if (!isfinite(rmx)) rmx = rs.x;
        if (!isfinite(rmy)) rmy = rs.y;
        float* rmid = ws;
        float* k1w  = ws + 2 * ROWS;
        float* s1w  = ws + 4 * ROWS;
        rmid[2*row]   = rmx; rmid[2*row+1] = rmy;
        k1w[2*row]    = k1x; k1w[2*row+1]  = k1y;
        s1w[row]      = D / dc;      // == sum of normalized score row
        bc[0]         = 1.f / dc;
    }
    __syncthreads();
    const float inv = bc[0];
    const float isx = rs.x * inv, isy = rs.y * inv;   // relu(dot)*inv == relu(dot*inv), inv>0

    // Score row: column-interleaved so each wave store instr is 1 KB contiguous.
    float* orow = score_out + (size_t)row * S_LEN;
    #pragma unroll
    for (int q = 0; q < 4; q++) {
        const int t0 = (threadIdx.x << 2) + (q << 10);   // 4*tid + 1024*q
        float4 v = make_float4(0.f, 0.f, 0.f, 0.f);
        if (t0 <= s) {
            float4 p01 = rb4[t0 >> 1];        // points t0, t0+1
            float4 p23 = rb4[(t0 >> 1) + 1];  // points t0+2, t0+3 (in-bounds: t0+3 <= 4095)
            v.x = fmaxf(isx * p01.x + isy * p01.y, 0.f);
            v.y = (t0 + 1 <= s) ? fmaxf(isx * p01.z + isy * p01.w, 0.f) : 0.f;
            v.z = (t0 + 2 <= s) ? fmaxf(isx * p23.x + isy * p23.y, 0.f) : 0.f;
            v.w = (t0 + 3 <= s) ? fmaxf(isx * p23.z + isy * p23.w, 0.f) : 0.f;
        }
        *((float4*)(orow + t0)) = v;
    }
}

__global__ __launch_bounds__(BLK) void k_pass2(
    const float2* __restrict__ r_in,
    const float* __restrict__ dt_in,
    const float* __restrict__ ws,
    float* __restrict__ rfinal_out)               // fp32, [ROWS, 2]
{
    __shared__ float red[12];

    const int row = blockIdx.x;
    const int b = row >> 12;
    const int s = row & (S_LEN - 1);
    const float2* rm = ((const float2*)ws) + ((size_t)b << 12);
    const float4* rm4 = (const float4*)rm;
    const float2 rs = rm[s];

    float dsum = 0.f, nx = 0.f, ny = 0.f;
    for (int i = threadIdx.x; 2*i <= s; i += BLK) {
        float4 p = rm4[i];
        float d0 = fmaxf(rs.x * p.x + rs.y * p.y, 0.f);
        dsum += d0; nx = fmaf(d0, p.x, nx); ny = fmaf(d0, p.y, ny);
        if (2*i + 1 <= s) {
            float d1 = fmaxf(rs.x * p.z + rs.y * p.w, 0.f);
            dsum += d1; nx = fmaf(d1, p.z, nx); ny = fmaf(d1, p.w, ny);
        }
    }
    reduce3(dsum, nx, ny, red);
    if (threadIdx.x == 0) {
        const float* k1w = ws + 2 * ROWS;
        const float* s1w = ws + 4 * ROWS;
        const float dc = fmaxf(dsum, EPSF);
        const float dtb = dt_in[b];
        float k2x = dtb * nx / dc;
        float k2y = dtb * ny / dc;
        if (!isfinite(k2x)) k2x = 0.f;
        if (!isfinite(k2y)) k2y = 0.f;
        const float2 r0 = r_in[row];
        const float k1x = k1w[2*row], k1y = k1w[2*row+1];
        const float rnx = r0.x + 0.5f * (k1x + k2x);
        const float rny = r0.y + 0.5f * (k1y + k2y);
        const float nr = fmaxf(sqrtf(rnx*rnx + rny*rny), EPSF);
        const float ar = fminf(fmaxf(nr + s1w[row] * RATE, MINR), MAXR);
        const float sc = ar / nr;
        float fx = rnx * sc, fy = rny * sc;
        if (!isfinite(fx)) fx = r0.x;
        if (!isfinite(fy)) fy = r0.y;
        rfinal_out[2*row]   = fx;
        rfinal_out[2*row+1] = fy;
    }
}

extern "C" void kernel_launch(void* const* d_in, const int* in_sizes, int n_in,
                              void* d_out, int out_size, void* d_ws, size_t ws_size,
                              hipStream_t stream) {
    const float2* r_in  = (const float2*)d_in[0];   // fp32 [4,4096,2]
    const float*  dt_in = (const float*)d_in[1];    // fp32 [4]
    float* out = (float*)d_out;
    float* ws  = (float*)d_ws;

    // d_out: first ROWS*2 floats = r_final, then ROWS*S_LEN floats = score.
    float* rfinal_out = out;
    float* score_out  = out + (size_t)2 * ROWS;

    hipLaunchKernelGGL(k_pass1, dim3(ROWS), dim3(BLK), 0, stream,
                       r_in, dt_in, ws, score_out);
    hipLaunchKernelGGL(k_pass2, dim3(ROWS), dim3(BLK), 0, stream,
                       r_in, dt_in, ws, rfinal_out);
}